// Round 1
// baseline (211.444 us; speedup 1.0000x reference)
//
#include <hip/hip_runtime.h>
#include <math.h>

// Round 4: fp16 MFMA im2col conv — staging/LDS rework.
// Theory: R3 was transaction-bound, not BW-bound. Two fixes:
//  (1) Staging lane map was channel-fastest -> each wave dword-load spanned
//      ~16 planes 512KB apart (16+ cache lines/instr). Now col-fastest:
//      each task loads 8 channel-batched dwords, every wave instruction
//      covers one contiguous ~256B row segment of ONE plane.
//  (2) LDS layout was [col][16ch] -> bfrag ds_read_b128 at 32B lane stride
//      = ~8-way bank conflict. Now [r][kg][col][8ch]: a lane's fragment is
//      16 CONTIGUOUS bytes -> natural conflict-free b128 read; staging
//      writes are one contiguous-slot ds_write_b128 per task (also clean).
// MFMA: D[32 filters x 32 pixels] via v_mfma_f32_32x32x16_f16, A=weights,
// B=pixels; K=144=9 taps x 16ch, 9 MFMAs per tile, fp32 accum.
// Block: 256 thr = 4 waves; tile 8 rows x 64 cols x 32 filters, one image.
// LDS: [10][2][72][8] fp16 = 23040 B -> 4 blocks/CU (launch_bounds cap).

typedef __attribute__((ext_vector_type(8)))  _Float16 half8;
typedef __attribute__((ext_vector_type(16))) float    float16v;

#define BLOCK 256
#define TW 64
#define TH 8
#define HROWS 10
#define HCOLS 66
#define PADW 72   // padded slot stride per (r,kg) row; slot = 16B = 8 halves

__device__ __forceinline__ float sigf(float z) {
    return 1.0f / (1.0f + __expf(-z));
}

extern "C" __global__ __launch_bounds__(BLOCK, 4)
void conv3x3_mfma(const float* __restrict__ xin,
                  const float* __restrict__ wgt,
                  const float* __restrict__ bias,
                  float* __restrict__ out) {
    __shared__ _Float16 sIn[2 * HROWS * PADW * 8];   // [r][kg][col][8ch], 23040 B

    const int tid = threadIdx.x;
    const int x0 = blockIdx.x * TW;
    const int y0 = blockIdx.y * TH;
    const int b  = blockIdx.z;

    // ---- stage input halo: fp32 NCHW -> fp16 LDS [r][kg][col][8ch]
    // task p -> (kg, colr); lanes sweep col fastest => each of the 8 global
    // loads per task is a contiguous, coalesced row segment of one plane.
    for (int p = tid; p < 2 * HROWS * HCOLS; p += BLOCK) {
        int kg = 0, colr = p;
        if (colr >= HROWS * HCOLS) { kg = 1; colr -= HROWS * HCOLS; }
        const int r   = colr / HCOLS;              // magic-div by 66
        const int col = colr - r * HCOLS;
        const int gy  = y0 - 1 + r;
        const int gx  = x0 - 1 + col;
        half8 hv = {};                             // OOB rows/cols stay zero
        if ((unsigned)gy < 256u && (unsigned)gx < 256u) {
            const float* px = &xin[((b * 16 + kg * 8) * 256 + gy) * 256 + gx];
            #pragma unroll
            for (int j = 0; j < 8; ++j)
                hv[j] = (_Float16)px[j * 65536];   // 8 channel planes
        }
        // one contiguous 16B slot per task -> conflict-free ds_write_b128
        *(half8*)&sIn[((r * 2 + kg) * PADW + col) * 8] = hv;
    }

    // ---- preload weight A-fragments: 9 taps x 8 channels (per lane)
    // A[m][k]: m = lane&31 = filter, k = (lane>>5)*8 + j = channel
    // wgt layout: [c*9 + tap][filter] (torch Unfold row order c,kh,kw)
    const int lane = tid & 63;
    const int f    = lane & 31;
    const int kg   = lane >> 5;
    half8 wfrag[9];
    #pragma unroll
    for (int t = 0; t < 9; ++t) {
        #pragma unroll
        for (int j = 0; j < 8; ++j) {
            int c = kg * 8 + j;
            wfrag[t][j] = (_Float16)wgt[(c * 9 + t) * 32 + f];
        }
    }

    __syncthreads();

    const int wv = tid >> 6;      // wave id 0..3
    const int px = lane & 31;     // pixel-within-tile (B-operand n)

    #pragma unroll 1
    for (int t4 = 0; t4 < 4; ++t4) {
        const int r = wv * 2 + (t4 >> 1);   // output row within tile
        const int h = t4 & 1;               // col half
        float16v acc = {};                  // fp32 accumulator, zeroed

        #pragma unroll
        for (int dy = 0; dy < 3; ++dy) {
            #pragma unroll
            for (int dx = 0; dx < 3; ++dx) {
                const int rh = r + dy;              // halo row 0..9
                const int ch = h * 32 + px + dx;    // halo col 0..65
                // lane's 8 channels are 16 contiguous bytes -> clean b128
                half8 bfrag = *(const half8*)&sIn[((rh * 2 + kg) * PADW + ch) * 8];
                acc = __builtin_amdgcn_mfma_f32_32x32x16_f16(
                          wfrag[dy * 3 + dx], bfrag, acc, 0, 0, 0);
            }
        }

        // ---- epilogue: C/D row = filter = (reg&3) + 8*(reg>>2) + 4*kg,
        // col = pixel = px. Lanes 0..31 are consecutive x -> coalesced.
        const int y  = y0 + r;
        const int xg = x0 + h * 32 + px;
        #pragma unroll
        for (int reg = 0; reg < 16; ++reg) {
            const int ff = (reg & 3) + 8 * (reg >> 2) + 4 * kg;
            const float bz = bias[(ff * 256 + y) * 256 + xg];
            out[((b * 32 + ff) * 256 + y) * 256 + xg] = sigf(acc[reg] + bz);
        }
    }
}

extern "C" void kernel_launch(void* const* d_in, const int* in_sizes, int n_in,
                              void* d_out, int out_size, void* d_ws, size_t ws_size,
                              hipStream_t stream) {
    const float* x    = (const float*)d_in[0];   // (16,16,256,256) fp32
    const float* w    = (const float*)d_in[1];   // (144,32) fp32
    const float* bias = (const float*)d_in[2];   // (32,256,256) fp32
    float* out = (float*)d_out;                  // (16,32,256,256) fp32

    dim3 grid(256 / TW, 256 / TH, 16);           // (4, 32, 16) = 2048 blocks
    conv3x3_mfma<<<grid, dim3(BLOCK), 0, stream>>>(x, w, bias, out);
}